// Round 7
// baseline (8985.336 us; speedup 1.0000x reference)
//
#include <hip/hip_runtime.h>

typedef unsigned short UST;
typedef unsigned int uint32;
typedef float f32x4 __attribute__((ext_vector_type(4)));
typedef short s16x8 __attribute__((ext_vector_type(8)));

// problem sizes: L=512 B=128 D=512 T=200 E=384 C=128 H=512 V=46

__device__ __forceinline__ float b2f(UST u) {
  uint32 x = ((uint32)u) << 16;
  union { uint32 u; float f; } v; v.u = x; return v.f;
}
__device__ __forceinline__ UST f2bf(float f) {
  union { float f; uint32 u; } v; v.f = f;
  uint32 r = (v.u + 0x7fffu + ((v.u >> 16) & 1u)) >> 16;
  return (UST)r;
}
__device__ __forceinline__ ushort4 f2bf4(float4 v) {
  ushort4 r; r.x = f2bf(v.x); r.y = f2bf(v.y); r.z = f2bf(v.z); r.w = f2bf(v.w); return r;
}
__device__ __forceinline__ float sigf(float x) { return 1.f / (1.f + __expf(-x)); }
__device__ __forceinline__ float tanhf_(float x) { return 2.f / (1.f + __expf(-2.f * x)) - 1.f; }

union U8 { unsigned long long u; ushort4 s; uint2 w; };

// coherent (IC-routed) accesses: relaxed agent atomics -> no cache inv/wb anywhere
__device__ __forceinline__ void st_flag(int* p, int v) {
  __hip_atomic_store(p, v, __ATOMIC_RELAXED, __HIP_MEMORY_SCOPE_AGENT);
}
__device__ __forceinline__ int ld_flag(const int* p) {
  return __hip_atomic_load(p, __ATOMIC_RELAXED, __HIP_MEMORY_SCOPE_AGENT);
}
__device__ __forceinline__ void st4(void* p, uint32 v) {
  __hip_atomic_store((uint32*)p, v, __ATOMIC_RELAXED, __HIP_MEMORY_SCOPE_AGENT);
}

// ---- WIDE coherent loads (sc1 = device-coherent, verified R6: observe agent atomics).
// 16 rows x 16B, row stride 1024B. 4 bases + offset imms. One asm block -> all in flight.
__device__ __forceinline__ void ld16x_h(const UST* p0, uint4 rg[16]) {
  const UST* p1 = p0 + 4 * 512;
  const UST* p2 = p0 + 8 * 512;
  const UST* p3 = p0 + 12 * 512;
  asm volatile(
    "global_load_dwordx4 %0, %16, off sc1\n\t"
    "global_load_dwordx4 %1, %16, off offset:1024 sc1\n\t"
    "global_load_dwordx4 %2, %16, off offset:2048 sc1\n\t"
    "global_load_dwordx4 %3, %16, off offset:3072 sc1\n\t"
    "global_load_dwordx4 %4, %17, off sc1\n\t"
    "global_load_dwordx4 %5, %17, off offset:1024 sc1\n\t"
    "global_load_dwordx4 %6, %17, off offset:2048 sc1\n\t"
    "global_load_dwordx4 %7, %17, off offset:3072 sc1\n\t"
    "global_load_dwordx4 %8, %18, off sc1\n\t"
    "global_load_dwordx4 %9, %18, off offset:1024 sc1\n\t"
    "global_load_dwordx4 %10, %18, off offset:2048 sc1\n\t"
    "global_load_dwordx4 %11, %18, off offset:3072 sc1\n\t"
    "global_load_dwordx4 %12, %19, off sc1\n\t"
    "global_load_dwordx4 %13, %19, off offset:1024 sc1\n\t"
    "global_load_dwordx4 %14, %19, off offset:2048 sc1\n\t"
    "global_load_dwordx4 %15, %19, off offset:3072 sc1\n\t"
    "s_waitcnt vmcnt(0)"
    : "=&v"(rg[0]), "=&v"(rg[1]), "=&v"(rg[2]), "=&v"(rg[3]),
      "=&v"(rg[4]), "=&v"(rg[5]), "=&v"(rg[6]), "=&v"(rg[7]),
      "=&v"(rg[8]), "=&v"(rg[9]), "=&v"(rg[10]), "=&v"(rg[11]),
      "=&v"(rg[12]), "=&v"(rg[13]), "=&v"(rg[14]), "=&v"(rg[15])
    : "v"(p0), "v"(p1), "v"(p2), "v"(p3)
    : "memory");
}
// 4 rows x 16B, row stride 256B (ctx rows)
__device__ __forceinline__ void ld4x_ctx(const UST* p0, uint4 rg[4]) {
  asm volatile(
    "global_load_dwordx4 %0, %4, off sc1\n\t"
    "global_load_dwordx4 %1, %4, off offset:256 sc1\n\t"
    "global_load_dwordx4 %2, %4, off offset:512 sc1\n\t"
    "global_load_dwordx4 %3, %4, off offset:768 sc1\n\t"
    "s_waitcnt vmcnt(0)"
    : "=&v"(rg[0]), "=&v"(rg[1]), "=&v"(rg[2]), "=&v"(rg[3])
    : "v"(p0) : "memory");
}
// single coherent 8B load (attend hx2 pickup)
__device__ __forceinline__ uint2 ld2c(const UST* p) {
  uint2 r;
  asm volatile("global_load_dwordx2 %0, %1, off sc1\n\ts_waitcnt vmcnt(0)"
               : "=&v"(r) : "v"(p) : "memory");
  return r;
}
__device__ __forceinline__ void lgkm0() {
  asm volatile("s_waitcnt lgkmcnt(0)" ::: "memory");
}

// block-wide signal (init/attend only)
__device__ __forceinline__ void signal_flag(int* fl, int idx, int val, int tid) {
  __atomic_signal_fence(__ATOMIC_SEQ_CST);
  __builtin_amdgcn_s_waitcnt(0);
  __atomic_signal_fence(__ATOMIC_SEQ_CST);
  __syncthreads();
  if (tid == 0) st_flag(&fl[idx * 16], val);
}
__device__ __forceinline__ void wait128f(int* fl, int val, int tid, unsigned long long dl) {
  if (tid < 128) {
    while (ld_flag(&fl[tid * 16]) < val) {
      if (__builtin_amdgcn_s_memrealtime() > dl) break;
      __builtin_amdgcn_s_sleep(1);
    }
  }
  __syncthreads();
}
// per-wave consumer poll: lane polls flag (producer js'=lane, wave w) of its m-half.
__device__ __forceinline__ void pollw(int* arr, int m64, int w, int val, int lane,
                                      unsigned long long dl) {
  const int* fp = &arr[((m64 + lane) * 4 + w) * 16];
  while (ld_flag(fp) < val) {
    if (__builtin_amdgcn_s_memrealtime() > dl) break;
    __builtin_amdgcn_s_sleep(1);
  }
}

struct Args {
  const float* lf; const int* ulen; const int* tr; const float* emb;
  const float* wih0; const float* whh0; const float* bih0; const float* bhh0;
  const float* wih1; const float* whh1; const float* bih1; const float* bhh1;
  const float* wih2; const float* whh2; const float* bih2; const float* bhh2;
  const float* phi_w; const float* phi_b; const float* key_w; const float* key_b;
  const float* val_w; const float* val_b; const float* out_w; const float* out_b;
  const float* ihx0; const float* icx0; const float* ihx1; const float* icx1;
  const float* ihx2; const float* icx2;
  int* bar; UST* wr; UST* xemb; UST* phi_bf; UST* keyfT; UST* valfT;
  UST* hx0; UST* hx1; UST* hx2; UST* ctx; UST* h2h; UST* cxh;
  float* out_logits; float* out_attn;
};

// ---------------- P1: zero flags, fragment-linear bf16 weights, xemb, phi_bf
// weight flat idx q: i=q&7 lane=(q>>3)&63 nt=(q>>9)&1 ks=(q>>10)&31 js=(q>>15)&63 cell=q>>21
// element = W[gr = js*32+nt*16+(lane&15)][k = ks*32+(lane>>4)*8+i], gate-row gr = jc*4+g
// cell0 x layout: [emb 0..383 | h0 384..895 | ctx 896..1023]
__global__ void __launch_bounds__(256) kprep(Args A) {
  const long N0 = 32768;            // flag ints (131072 B)
  const long N1 = 3L * 2048 * 1024; // weights
  const long N2 = 200L * 128 * 384; // xemb
  const long N3 = 128L * 512;       // phi
  long total = N0 + N1 + N2 + N3;
  long stride = (long)gridDim.x * blockDim.x;
  for (long ii = (long)blockIdx.x * 256 + threadIdx.x; ii < total; ii += stride) {
    long j = ii;
    if (j < N0) { A.bar[j] = 0; continue; }
    j -= N0;
    if (j < N1) {
      int q = (int)j;
      int i = q & 7, lane = (q >> 3) & 63, nt = (q >> 9) & 1, ks = (q >> 10) & 31;
      int js = (q >> 15) & 63, cell = q >> 21;
      int gr = js * 32 + nt * 16 + (lane & 15);
      int jc = gr >> 2, g = gr & 3, k = ks * 32 + (lane >> 4) * 8 + i;
      const float* wi = cell == 0 ? A.wih0 : cell == 1 ? A.wih1 : A.wih2;
      const float* wh = cell == 0 ? A.whh0 : cell == 1 ? A.whh1 : A.whh2;
      float v;
      if (cell == 0)
        v = (k < 384) ? wi[(g * 512 + jc) * 512 + k]
          : (k < 896) ? wh[(g * 512 + jc) * 512 + k - 384]
                      : wi[(g * 512 + jc) * 512 + k - 512];
      else
        v = (k < 512) ? wi[(g * 512 + jc) * 512 + k] : wh[(g * 512 + jc) * 512 + k - 512];
      A.wr[j] = f2bf(v);
      continue;
    }
    j -= N1;
    if (j < N2) {
      int t = (int)(j / 49152); int r = (int)(j % 49152); int bb = r / 384; int e = r - bb * 384;
      int ch = (t == 0) ? 0 : A.tr[(t - 1) * 128 + bb];
      A.xemb[j] = f2bf(A.emb[ch * 384 + e]);
      continue;
    }
    j -= N2;
    A.phi_bf[j] = f2bf(A.phi_w[j]);
  }
}

// ---------------- P2: keyfT/valfT = (lf . W^T + b), stored [B][C][L] bf16
__global__ void __launch_bounds__(256) kkv(Args A) {
  __shared__ __attribute__((aligned(16))) char sm[17408 + 34816];
  UST (*A_lds)[136] = (UST(*)[136])sm;
  UST (*W_lds)[136] = (UST(*)[136])(sm + 17408);
  float* sbuf = (float*)(sm + 17408);
  int tid = threadIdx.x, lane = tid & 63, wv = tid >> 6, ln = lane & 15, qd = lane >> 4;
  int blk = blockIdx.x;
  int b = blk >> 4, lt = (blk >> 1) & 7, kv = blk & 1;
  int l0 = lt * 64;
  const float* W = kv ? A.val_w : A.key_w;
  const float* bs = kv ? A.val_b : A.key_b;
  UST* outp = kv ? A.valfT : A.keyfT;
  f32x4 acc[8];
#pragma unroll
  for (int nt = 0; nt < 8; ++nt) {
    float x = bs[nt * 16 + ln];
    f32x4 t; t[0] = x; t[1] = x; t[2] = x; t[3] = x; acc[nt] = t;
  }
  for (int cc = 0; cc < 4; ++cc) {
    int d0 = cc * 128;
#pragma unroll
    for (int it = 0; it < 8; ++it) {
      int idx = it * 256 + tid, row = idx >> 5, seg = idx & 31;
      float4 v = *(const float4*)(A.lf + ((size_t)(l0 + row) * 128 + b) * 512 + d0 + seg * 4);
      *(ushort4*)&A_lds[row][seg * 4] = f2bf4(v);
    }
#pragma unroll
    for (int it = 0; it < 16; ++it) {
      int idx = it * 256 + tid, row = idx >> 5, seg = idx & 31;
      float4 v = *(const float4*)(W + (size_t)row * 512 + d0 + seg * 4);
      *(ushort4*)&W_lds[row][seg * 4] = f2bf4(v);
    }
    __syncthreads();
#pragma unroll
    for (int ks = 0; ks < 4; ++ks) {
      s16x8 av = *(const s16x8*)&A_lds[wv * 16 + ln][ks * 32 + qd * 8];
#pragma unroll
      for (int nt = 0; nt < 8; ++nt) {
        s16x8 bv = *(const s16x8*)&W_lds[nt * 16 + ln][ks * 32 + qd * 8];
        acc[nt] = __builtin_amdgcn_mfma_f32_16x16x32_bf16(av, bv, acc[nt], 0, 0, 0);
      }
    }
    __syncthreads();
  }
#pragma unroll
  for (int nt = 0; nt < 8; ++nt)
#pragma unroll
    for (int r = 0; r < 4; ++r)
      sbuf[(wv * 16 + qd * 4 + r) * 128 + nt * 16 + ln] = acc[nt][r];
  __syncthreads();
  int c2 = tid >> 1, lh = tid & 1;
  for (int g8 = 0; g8 < 4; ++g8) {
    UST tmp[8];
#pragma unroll
    for (int i = 0; i < 8; ++i) tmp[i] = f2bf(sbuf[(lh * 32 + g8 * 8 + i) * 128 + c2]);
    *(uint4*)(outp + ((size_t)b * 128 + c2) * 512 + l0 + lh * 32 + g8 * 8) = *(uint4*)tmp;
  }
}

// ---------------- wave-autonomous cell machinery.
// Wave w owns batch rows 16w..16w+15 and the block's 8 h-cols over the FULL K.
// LDS band per wave: 16KB = [16 rows][64 chunk-cols][16B], XOR-swizzled (col^(row&7)).
// Staging: lane stages col=lane for the wave's 16 rows (one fused wide-load).
// Compute: A-frag = band[row=lane&15][(k*4 + lane>>4)^swz]; B-frag from weights; 2 MFMA/ksg.
// Epilogue: wave-local — bias + shfl_xor gate-gather + nonlin (g==0 lanes) + 256B LDS
// pack + 16x16B coherent store + own-wave vmcnt drain + per-wave flag. NO barriers.
__device__ __forceinline__ void bandwr(char* band, int lane, const uint4 rg[16]) {
#pragma unroll
  for (int r = 0; r < 16; ++r)
    *(uint4*)(band + r * 1024 + (lane ^ (r & 7)) * 16) = rg[r];
}
template <int NK>
__device__ __forceinline__ void comp_band(const char* band, int ln, int qd, int lane,
    const UST* wb, int ksgBase, f32x4 acc[2]) {
#pragma unroll
  for (int k = 0; k < NK; ++k) {
    int ksg = ksgBase + k;
    int cb = k * 4 + qd;
    s16x8 a = *(const s16x8*)(band + ln * 1024 + ((cb ^ (ln & 7))) * 16);
    s16x8 b0 = *(const s16x8*)(wb + ((size_t)(ksg * 2 + 0) * 64 + lane) * 8);
    s16x8 b1 = *(const s16x8*)(wb + ((size_t)(ksg * 2 + 1) * 64 + lane) * 8);
    acc[0] = __builtin_amdgcn_mfma_f32_16x16x32_bf16(a, b0, acc[0], 0, 0, 0);
    acc[1] = __builtin_amdgcn_mfma_f32_16x16x32_bf16(a, b1, acc[1], 0, 0, 0);
  }
}
__device__ __forceinline__ void zacc2(f32x4 a[2]) {
  a[0][0]=0.f; a[0][1]=0.f; a[0][2]=0.f; a[0][3]=0.f;
  a[1][0]=0.f; a[1][1]=0.f; a[1][2]=0.f; a[1][3]=0.f;
}
// gate layout per lane: gr_local = nt*16 + (lane&15) -> jc = nt*4 + ((lane&15)>>2),
// g = (lane&15)&3; output row = 16w + (lane>>4)*4 + reg. Gates of one (row,jc) live in
// lanes (lane&~3)|{0..3}: gather with shfl_xor 1,2; g==0 lanes compute & write.
__device__ __forceinline__ void epi_wave(const Args& A, int cell, int t, int m64, int w16,
    int lane, int ln, int qd, int j0, f32x4 acc[2], const float biasL[2], float (*cr)[4],
    char* band, UST* hdst, int* flg, int fv) {
#pragma unroll
  for (int nt = 0; nt < 2; ++nt) {
#pragma unroll
    for (int reg = 0; reg < 4; ++reg) {
      float v = acc[nt][reg] + biasL[nt];
      float s1 = __shfl_xor(v, 1);
      float s2 = __shfl_xor(v, 2);
      float s3 = __shfl_xor(s1, 2);
      // valid in g==0 lanes: v=i, s1=f, s2=g, s3=o
      float cn = sigf(s1) * cr[nt][reg] + sigf(v) * tanhf_(s2);
      float hv = sigf(s3) * tanhf_(cn);
      cr[nt][reg] = cn;
      if ((ln & 3) == 0)
        *(UST*)(band + (qd * 4 + reg) * 16 + (nt * 4 + (ln >> 2)) * 2) = f2bf(hv);
    }
  }
  lgkm0();  // wave-local LDS exchange: all lanes' writes done before reads below
  if (lane < 16) {
    uint4 hh = *(const uint4*)(band + lane * 16);
    int grow = m64 + w16 + lane;
    UST* d = hdst + (size_t)grow * 512 + j0;
    st4(d + 0, hh.x); st4(d + 2, hh.y); st4(d + 4, hh.z); st4(d + 6, hh.w);
    if (cell == 2)
      *(uint4*)(A.h2h + ((size_t)t * 128 + grow) * 512 + j0) = hh;
  }
  __atomic_signal_fence(__ATOMIC_SEQ_CST);
  __builtin_amdgcn_s_waitcnt(0);  // own-wave drain only — no barrier
  __atomic_signal_fence(__ATOMIC_SEQ_CST);
  if (lane == 0) st_flag(flg, fv);
}

// ---------------- attention (blocks 128..255, one batch row each)
// K and V in registers; hx2 pickup polls this thread's (producer js', wave-band) flag.
__device__ __forceinline__ void attend_f(const Args& A, int t, int p, int b, int tid,
    int lane, int wv, char* smraw, const uint4 (&rgK)[32], const uint4 (&rgV)[32],
    const int* fp, int pv, unsigned long long dl) {
  float* att_h = (float*)smraw;                       // 512
  float* att_q = att_h + 512;                         // 256
  float* att_c = att_q + 256;                         // 128
  float* att_red = att_c + 128;                       // 16
  float (*e_part)[512] = (float(*)[512])(att_red + 16);
  const UST* hx2p = A.hx2 + p * 65536;
  if (tid < 128) {
    while (ld_flag(fp) < pv) {
      if (__builtin_amdgcn_s_memrealtime() > dl) break;
      __builtin_amdgcn_s_sleep(1);
    }
    U8 v; v.w = ld2c(hx2p + b * 512 + tid * 4);
    att_h[tid * 4 + 0] = b2f(v.s.x); att_h[tid * 4 + 1] = b2f(v.s.y);
    att_h[tid * 4 + 2] = b2f(v.s.z); att_h[tid * 4 + 3] = b2f(v.s.w);
  }
  __syncthreads();
  int c = tid & 127, half = tid >> 7;
  { // q = phi_b + phi . hx2
    float acc = half ? 0.f : A.phi_b[c];
    const UST* pr = A.phi_bf + c * 512 + half * 256;
    const float* hh = att_h + half * 256;
#pragma unroll 4
    for (int k = 0; k < 256; k += 8) {
      uint4 v = *(const uint4*)(pr + k);
      const UST* us = (const UST*)&v;
#pragma unroll
      for (int i = 0; i < 8; ++i) acc += b2f(us[i]) * hh[k + i];
    }
    att_q[tid] = acc;
  }
  __syncthreads();
  if (tid < 128) att_q[tid] += att_q[tid + 128];
  __syncthreads();
  { // energies from K registers
    int cg = tid >> 6, lg = tid & 63;
    float ep[8] = {0, 0, 0, 0, 0, 0, 0, 0};
#pragma unroll
    for (int i = 0; i < 32; ++i) {
      float qv = att_q[cg * 32 + i];
      const UST* us = (const UST*)&rgK[i];
#pragma unroll
      for (int j = 0; j < 8; ++j) ep[j] += qv * b2f(us[j]);
    }
#pragma unroll
    for (int i = 0; i < 8; ++i) e_part[cg][lg * 8 + i] = ep[i];
  }
  __syncthreads();
  float e0 = e_part[0][2 * tid] + e_part[1][2 * tid] + e_part[2][2 * tid] + e_part[3][2 * tid];
  float e1 = e_part[0][2 * tid + 1] + e_part[1][2 * tid + 1] + e_part[2][2 * tid + 1] + e_part[3][2 * tid + 1];
  float mx = fmaxf(e0, e1);
#pragma unroll
  for (int off = 32; off; off >>= 1) mx = fmaxf(mx, __shfl_xor(mx, off));
  if (lane == 0) att_red[wv] = mx;
  __syncthreads();
  mx = fmaxf(fmaxf(att_red[0], att_red[1]), fmaxf(att_red[2], att_red[3]));
  int len = A.ulen[b];
  float x0 = (2 * tid < len) ? __expf(e0 - mx) : 0.f;
  float x1 = (2 * tid + 1 < len) ? __expf(e1 - mx) : 0.f;
  float s = x0 + x1;
#pragma unroll
  for (int off = 32; off; off >>= 1) s += __shfl_xor(s, off);
  if (lane == 0) att_red[8 + wv] = s;
  __syncthreads();
  s = att_red[8] + att_red[9] + att_red[10] + att_red[11];
  float inv = 1.f / fmaxf(s, 1e-12f);
  float a0 = x0 * inv, a1 = x1 * inv;
  float* esm = &e_part[0][0];
  esm[2 * tid] = a0; esm[2 * tid + 1] = a1;
  if (t >= 0) {
    float2 st; st.x = a0; st.y = a1;
    *(float2*)(A.out_attn + ((size_t)t * 128 + b) * 512 + 2 * tid) = st;
  }
  __syncthreads();
  { // ctx[c] from V registers
    float acc = 0.f;
    const float* aa = esm + half * 256;
#pragma unroll
    for (int i = 0; i < 32; ++i) {
      const UST* us = (const UST*)&rgV[i];
#pragma unroll
      for (int j = 0; j < 8; ++j) acc += aa[i * 8 + j] * b2f(us[j]);
    }
    att_q[tid] = acc;
  }
  __syncthreads();
  if (tid < 128) att_c[tid] = att_q[tid] + att_q[tid + 128];
  __syncthreads();
  if (tid < 64) {
    float cv0 = att_c[2 * tid], cv1 = att_c[2 * tid + 1];
    uint32 u = (uint32)f2bf(cv0) | ((uint32)f2bf(cv1) << 16);
    st4(A.ctx + p * 16384 + b * 128 + 2 * tid, u);
    if (t >= 0) *(uint32*)(A.cxh + ((size_t)t * 128 + b) * 128 + 2 * tid) = u;
  }
}

// ---------------- main persistent kernel. PLAIN launch; co-residency by capacity
// (LDS 64KB, grid 256 <= 256 CUs, 1 block/CU). Steady state: cell blocks have ZERO
// __syncthreads — each wave free-runs the whole chain, coupled only via per-wave flags
// (arrays of 2m x 64js x 4w, 64B-spaced). The machine decomposes into 8 independent
// cohorts (m x row-band); straggle unit = 64 waves + 16 attend blocks, not 128 blocks.
// Per-wave schedule per step t:
//   A: emb(t)+h0lo [no poll] -> c0 ksg0..15 | B: h0hi -> c0 ksg16..27
//   C1pre: h1(t-1) [no poll] -> c1 ksg16..31 | C2pre: [poll c2 t+1] h2(t-1) -> c2 ksg16..31
//   ctx: [poll attf rows t+1] -> c0 ksg28..31 ; epi0 -> flag c0[js,w]=t+2
//   seg3: [poll c0 t+2] h0(t) -> c1 ksg0..15 ; epi1 -> flag c1
//   seg4: [poll c1 t+2] h1(t) -> c2 ksg0..15 ; epi2 -> flag c2 (+h2h)
__global__ void __launch_bounds__(256, 1) kmain(Args A) {
  __shared__ __attribute__((aligned(16))) char smraw[65536];
  unsigned long long dl = __builtin_amdgcn_s_memrealtime() + 100000000ull;
  int blk = blockIdx.x, tid = threadIdx.x;
  int lane = tid & 63, w = tid >> 6, ln = lane & 15, qd = lane >> 4;
  int* c0f4 = A.bar;             // 512 x 16 ints
  int* c1f4 = A.bar + 8192;
  int* c2f4 = A.bar + 16384;
  int* attf = A.bar + 24576;     // 128 x 16
  int* initf = A.bar + 26624;    // 128 x 16
  if (blk < 128) {
    char* band = smraw + w * 16384;
    int js = ((blk >> 4) << 3) | (blk & 7);
    int m = (blk >> 3) & 1;
    int j0 = js * 8;
    int sid = m * 64 + js;
    int m64 = m * 64;
    int w16 = w * 16;
    // per-lane bias (own gate g = ln&3, cols j0 + nt*4 + (ln>>2)) and c-state
    float biasL[3][2]; float cr[3][2][4];
    {
      const float* bihA[3] = {A.bih0, A.bih1, A.bih2};
      const float* bhhA[3] = {A.bhh0, A.bhh1, A.bhh2};
      const float* icxA[3] = {A.icx0, A.icx1, A.icx2};
      const float* ihxA[3] = {A.ihx0, A.ihx1, A.ihx2};
      UST* hxA[3] = {A.hx0, A.hx1, A.hx2};
      int gL = ln & 3, jcl = ln >> 2;
#pragma unroll
      for (int cI = 0; cI < 3; ++cI) {
#pragma unroll
        for (int nt = 0; nt < 2; ++nt) {
          int col = j0 + nt * 4 + jcl;
          biasL[cI][nt] = bihA[cI][gL * 512 + col] + bhhA[cI][gL * 512 + col];
#pragma unroll
          for (int reg = 0; reg < 4; ++reg) cr[cI][nt][reg] = icxA[cI][col];
        }
        // init h into slot 1 (block-coop, rows of this m-half x 8 cols)
        int row = tid >> 2, grow = m64 + row, q4 = tid & 3, col0 = j0 + q4 * 2;
        uint32 u = (uint32)f2bf(ihxA[cI][col0]) | ((uint32)f2bf(ihxA[cI][col0 + 1]) << 16);
        st4(hxA[cI] + 65536 + grow * 512 + col0, u);
      }
    }
    signal_flag(initf, sid, 1, tid);
    wait128f(initf, 1, tid, dl);
    if (lane == 0) {  // per-wave flags -> 1 (init data globally visible now)
      st_flag(&c0f4[(sid * 4 + w) * 16], 1);
      st_flag(&c1f4[(sid * 4 + w) * 16], 1);
      st_flag(&c2f4[(sid * 4 + w) * 16], 1);
    }
    const UST* wrj0 = A.wr + (size_t)js * 32768;
    const UST* wrj1 = wrj0 + 2097152;
    const UST* wrj2 = wrj0 + 4194304;
    int* myc0 = &c0f4[(sid * 4 + w) * 16];
    int* myc1 = &c1f4[(sid * 4 + w) * 16];
    int* myc2 = &c2f4[(sid * 4 + w) * 16];
    for (int t = 0; t < 200; ++t) {
      int p = t & 1, po = p ^ 1;
      const UST* xe = A.xemb + (size_t)t * 49152 + m64 * 384;
      const UST* h0r = A.hx0 + po * 65536 + m64 * 512;
      const UST* h1r = A.hx1 + po * 65536 + m64 * 512;
      const UST* h2r = A.hx2 + po * 65536 + m64 * 512;
      const UST* cxr = A.ctx + po * 16384 + m64 * 128;
      f32x4 acc0[2], acc1[2], acc2[2];
      zacc2(acc0); zacc2(acc1); zacc2(acc2);
      // A: emb cols 0..47 + h0(t-1) cols 0..15 (chunks 48..63); fresh via last step
      {
        uint4 rg[16];
        if (lane < 48) {
#pragma unroll
          for (int r = 0; r < 16; ++r)
            rg[r] = *(const uint4*)(xe + (size_t)(w16 + r) * 384 + lane * 8);
        } else {
          ld16x_h(h0r + (size_t)w16 * 512 + (lane - 48) * 8, rg);
        }
        bandwr(band, lane, rg);
      }
      lgkm0();
      comp_band<16>(band, ln, qd, lane, wrj0, 0, acc0);
      // B: h0(t-1) cols 16..63 -> band cols 0..47
      {
        uint4 rg[16];
        if (lane < 48) {
          ld16x_h(h0r + (size_t)w16 * 512 + (lane + 16) * 8, rg);
          bandwr(band, lane, rg);
        }
      }
      lgkm0();
      comp_band<12>(band, ln, qd, lane, wrj0, 16, acc0);
      // C1pre: h1(t-1) all 64 cols
      { uint4 rg[16]; ld16x_h(h1r + (size_t)w16 * 512 + lane * 8, rg); bandwr(band, lane, rg); }
      lgkm0();
      comp_band<16>(band, ln, qd, lane, wrj1, 16, acc1);
      // C2pre: poll + h2(t-1)
      pollw(c2f4, m64, w, t + 1, lane, dl);
      { uint4 rg[16]; ld16x_h(h2r + (size_t)w16 * 512 + lane * 8, rg); bandwr(band, lane, rg); }
      lgkm0();
      comp_band<16>(band, ln, qd, lane, wrj2, 16, acc2);
      // ctx: poll attend rows, stage 16 cols x 16 rows (4 rows/lane)
      {
        int cc = lane & 15, rq = lane >> 4;
        for (;;) {
          bool ok = true;
#pragma unroll
          for (int rr = 0; rr < 4; ++rr)
            ok &= (ld_flag(&attf[(m64 + w16 + rq * 4 + rr) * 16]) >= t + 1);
          if (ok) break;
          if (__builtin_amdgcn_s_memrealtime() > dl) break;
          __builtin_amdgcn_s_sleep(1);
        }
        uint4 rg4[4];
        ld4x_ctx(cxr + (size_t)(w16 + rq * 4) * 128 + cc * 8, rg4);
#pragma unroll
        for (int rr = 0; rr < 4; ++rr) {
          int r = rq * 4 + rr;
          *(uint4*)(band + r * 1024 + ((cc ^ (r & 7))) * 16) = rg4[rr];
        }
      }
      lgkm0();
      comp_band<4>(band, ln, qd, lane, wrj0, 28, acc0);
      epi_wave(A, 0, t, m64, w16, lane, ln, qd, j0, acc0, biasL[0], cr[0], band,
               A.hx0 + p * 65536, myc0, t + 2);
      // seg3: h0(t) -> cell1 ksg0..15
      pollw(c0f4, m64, w, t + 2, lane, dl);
      const UST* h0n = A.hx0 + p * 65536 + m64 * 512;
      { uint4 rg[16]; ld16x_h(h0n + (size_t)w16 * 512 + lane * 8, rg); bandwr(band, lane, rg); }
      lgkm0();
      comp_band<16>(band, ln, qd, lane, wrj1, 0, acc1);
      epi_wave(A, 1, t, m64, w16, lane, ln, qd, j0, acc1, biasL[1], cr[1], band,
               A.hx1 + p * 65536, myc1, t + 2);
      // seg4: h1(t) -> cell2 ksg0..15
      pollw(c1f4, m64, w, t + 2, lane, dl);
      const UST* h1n = A.hx1 + p * 65536 + m64 * 512;
      { uint4 rg[16]; ld16x_h(h1n + (size_t)w16 * 512 + lane * 8, rg); bandwr(band, lane, rg); }
      lgkm0();
      comp_band<16>(band, ln, qd, lane, wrj2, 0, acc2);
      epi_wave(A, 2, t, m64, w16, lane, ln, qd, j0, acc2, biasL[2], cr[2], band,
               A.hx2 + p * 65536, myc2, t + 2);
    }
  } else {
    int b = blk - 128;
    int m = b >> 6, wb = (b & 63) >> 4;
    // per-thread hx2 producer flag (tid<128): (m, js'=tid>>1, wave wb)
    const int* myf = &c2f4[(((m * 64) + (tid >> 1)) * 4 + wb) * 16];
    // preload K,V into registers (kkv completed before kmain)
    uint4 rgK[32], rgV[32];
    {
      int cg = tid >> 6, lg = tid & 63;
      const UST* kb = A.keyfT + (size_t)b * 65536 + lg * 8;
#pragma unroll
      for (int i = 0; i < 32; ++i)
        rgK[i] = *(const uint4*)(kb + (size_t)(cg * 32 + i) * 512);
      int c = tid & 127, half = tid >> 7;
      const UST* vb = A.valfT + (size_t)b * 65536 + (size_t)c * 512 + half * 256;
#pragma unroll
      for (int i = 0; i < 32; ++i)
        rgV[i] = *(const uint4*)(vb + i * 8);
    }
    wait128f(initf, 1, tid, dl);
    attend_f(A, -1, 1, b, tid, lane, w, smraw, rgK, rgV, myf, 1, dl);
    signal_flag(attf, b, 1, tid);
    for (int t = 0; t < 200; ++t) {
      attend_f(A, t, t & 1, b, tid, lane, w, smraw, rgK, rgV, myf, t + 2, dl);
      signal_flag(attf, b, t + 2, tid);
    }
  }
}

// ---------------- epilogue: logits[t,b,v] = [hx2,ctx] . out_w^T + out_b
__global__ void __launch_bounds__(256) kepi(Args A) {
  __shared__ UST ow[46 * 648];
  __shared__ float ob[46];
  int t = blockIdx.x, tid = threadIdx.x;
  for (int i = tid; i < 46 * 640; i += 256) {
    int v = i / 640, k = i - v * 640; ow[v * 648 + k] = f2bf(A.out_w[i]);
  }
  if (tid < 46) ob[tid] = A.out_b[tid];
  __syncthreads();
  for (int oi = tid; oi < 128 * 46; oi += 256) {
    int bb = oi / 46, v = oi - bb * 46;
    const UST* xh = A.h2h + ((size_t)t * 128 + bb) * 512;
    const UST* xc = A.cxh + ((size_t)t * 128 + bb) * 128;
    const UST* wrow = &ow[v * 648];
    float acc = ob[v];
    for (int k = 0; k < 512; k += 8) {
      uint4 xv = *(const uint4*)(xh + k);
      uint4 wv4 = *(const uint4*)(wrow + k);
      const UST* xs = (const UST*)&xv; const UST* wl = (const UST*)&wv4;
#pragma unroll
      for (int i = 0; i < 8; ++i) acc += b2f(xs[i]) * b2f(wl[i]);
    }
    for (int k = 0; k < 128; k += 8) {
      uint4 xv = *(const uint4*)(xc + k);
      uint4 wv4 = *(const uint4*)(wrow + 512 + k);
      const UST* xs = (const UST*)&xv; const UST* wl = (const UST*)&wv4;
#pragma unroll
      for (int i = 0; i < 8; ++i) acc += b2f(xs[i]) * b2f(wl[i]);
    }
    A.out_logits[((size_t)t * 128 + bb) * 46 + v] = acc;
  }
}

extern "C" void kernel_launch(void* const* d_in, const int* in_sizes, int n_in,
                              void* d_out, int out_size, void* d_ws, size_t ws_size,
                              hipStream_t stream) {
  (void)in_sizes; (void)n_in; (void)out_size; (void)ws_size;
  Args a;
  a.lf = (const float*)d_in[0]; a.ulen = (const int*)d_in[1]; a.tr = (const int*)d_in[2];
  a.emb = (const float*)d_in[3];
  a.wih0 = (const float*)d_in[4]; a.whh0 = (const float*)d_in[5]; a.bih0 = (const float*)d_in[6]; a.bhh0 = (const float*)d_in[7];
  a.wih1 = (const float*)d_in[8]; a.whh1 = (const float*)d_in[9]; a.bih1 = (const float*)d_in[10]; a.bhh1 = (const float*)d_in[11];
  a.wih2 = (const float*)d_in[12]; a.whh2 = (const float*)d_in[13]; a.bih2 = (const float*)d_in[14]; a.bhh2 = (const float*)d_in[15];
  a.phi_w = (const float*)d_in[16]; a.phi_b = (const float*)d_in[17];
  a.key_w = (const float*)d_in[18]; a.key_b = (const float*)d_in[19];
  a.val_w = (const float*)d_in[20]; a.val_b = (const float*)d_in[21];
  a.out_w = (const float*)d_in[22]; a.out_b = (const float*)d_in[23];
  a.ihx0 = (const float*)d_in[24]; a.icx0 = (const float*)d_in[25];
  a.ihx1 = (const float*)d_in[26]; a.icx1 = (const float*)d_in[27];
  a.ihx2 = (const float*)d_in[28]; a.icx2 = (const float*)d_in[29];
  char* ws = (char*)d_ws;
  a.bar    = (int*)ws;                   // 131,072 B (per-wave flag arrays + attf + initf)
  a.wr     = (UST*)(ws + 131072);        // 12,582,912 B
  a.xemb   = (UST*)(ws + 12713984);      // 19,660,800 B
  a.phi_bf = (UST*)(ws + 32374784);      // 131,072 B
  a.keyfT  = (UST*)(ws + 32505856);      // 16,777,216 B
  a.valfT  = (UST*)(ws + 49283072);      // 16,777,216 B
  a.hx0    = (UST*)(ws + 66060288);      // 262,144 B (2 slots)
  a.hx1    = (UST*)(ws + 66322432);      // 262,144 B
  a.hx2    = (UST*)(ws + 66584576);      // 262,144 B
  a.ctx    = (UST*)(ws + 66846720);      // 65,536 B (2 slots)
  a.h2h    = (UST*)(ws + 66912256);      // 26,214,400 B
  a.cxh    = (UST*)(ws + 93126656);      // 6,553,600 B -> total 99,680,256 B
  a.out_logits = (float*)d_out;
  a.out_attn   = (float*)d_out + 1177600;
  kprep<<<4096, 256, 0, stream>>>(a);
  kkv<<<2048, 256, 0, stream>>>(a);
  kmain<<<256, 256, 0, stream>>>(a);
  kepi<<<200, 256, 0, stream>>>(a);
}